// Round 17
// baseline (526.917 us; speedup 1.0000x reference)
//
#include <hip/hip_runtime.h>
#include <math.h>

#define DM 512
#define NTOK_V 62

typedef _Float16 h16;
typedef __attribute__((ext_vector_type(8))) _Float16 h16x8;
typedef __attribute__((ext_vector_type(4))) float f32x4;

__device__ __forceinline__ void ldsload16(const void* g, void* l) {
    __builtin_amdgcn_global_load_lds(
        (const __attribute__((address_space(1))) unsigned int*)g,
        (__attribute__((address_space(3))) unsigned int*)l, 16, 0, 0);
}

// XCD-chunked bijective blockIdx swizzle (T1; requires nwg%8==0 per z-plane).
// Scheme: XCD k owns token rows [k*1024,(k+1)*1024).
__device__ __forceinline__ void xcd_swz(int& bx, int& by) {
    const int gx = gridDim.x, gy = gridDim.y;
    const int lin = blockIdx.x + gx * blockIdx.y;
    const int cpx = (gx * gy) >> 3;
    const int wg = (lin & 7) * cpx + (lin >> 3);
    bx = wg % gx;
    by = wg / gx;
}

// ---------------------------------------------------------------- fused fp32 -> fp16 weight convert
__global__ __launch_bounds__(256) void k_cvt_all(const float* __restrict__ s0,
                                                 const float* __restrict__ s1,
                                                 const float* __restrict__ s2,
                                                 const float* __restrict__ s3,
                                                 h16* __restrict__ dst) {
    int i = blockIdx.x * 256 + threadIdx.x;
    const float* src;
    int off;
    if (i < 393216)       { src = s0; off = i; }
    else if (i < 524288)  { src = s1; off = i - 393216; }
    else if (i < 1048576) { src = s2; off = i - 524288; }
    else                  { src = s3; off = i - 1048576; }
    float4 a = ((const float4*)src)[off * 2];
    float4 b = ((const float4*)src)[off * 2 + 1];
    h16x8 h;
    h[0] = (h16)a.x; h[1] = (h16)a.y; h[2] = (h16)a.z; h[3] = (h16)a.w;
    h[4] = (h16)b.x; h[5] = (h16)b.y; h[6] = (h16)b.z; h[7] = (h16)b.w;
    ((h16x8*)dst)[i] = h;
}

// ---------------------------------------------------------------- concat -> fp16 X (XCD-aligned rows)
__global__ __launch_bounds__(256) void k_concat_h(const float* __restrict__ frames,
                                                  const float* __restrict__ expt,
                                                  h16* __restrict__ X) {
    int row = ((blockIdx.x & 7) << 10) + (blockIdx.x >> 3);
    int b = row >> 5, s = row & 31;
    int t = threadIdx.x;
    const float* src = (s < 30) ? (frames + ((size_t)(b * 30 + s)) * DM)
                                : (expt + (size_t)(s - 30) * DM);
    X[(size_t)row * DM + t]       = (h16)src[t];
    X[(size_t)row * DM + t + 256] = (h16)src[t + 256];
}

// ---------------------------------------------------------------- 8-phase 256x256 MFMA GEMM (R9/R10-proven)
template<int MODE>   // 0 = +bias, 1 = +bias+relu
__global__ __launch_bounds__(512, 2) void k_g8(
        const h16* __restrict__ A, int lda,
        const h16* __restrict__ B, int ldb,
        const float* __restrict__ bias,
        h16* __restrict__ C, int ldc,
        int M, int N, int Keff) {
    __shared__ char smem[131072];
    const int t = threadIdx.x;
    const int w = t >> 6, lane = t & 63;
    const int wr = w >> 2, wc = w & 3;
    const int kc = lane >> 4, rr = lane & 15;
    int bx, by;
    xcd_swz(bx, by);
    const size_t row0 = (size_t)by * 256;
    const size_t col0 = (size_t)bx * 256;

    const h16* gA = A + (row0 + (w << 4) + rr) * (size_t)lda + (kc << 3);
    const h16* gB = B + (col0 + (w << 4) + rr) * (size_t)ldb + (kc << 3);

    f32x4 acc[8][4];
#pragma unroll
    for (int m = 0; m < 8; ++m)
#pragma unroll
        for (int n = 0; n < 4; ++n) acc[m][n] = (f32x4){0.f, 0.f, 0.f, 0.f};

    const int nt = Keff >> 6;

#define SB0 __builtin_amdgcn_sched_barrier(0);
#define STG_A(bs, h, jt) { char* d_ = smem + (bs)*65536 + (h)*16384 + (w << 10) + (lane << 4); \
        const h16* s_ = gA + (size_t)((h)*128) * lda + (size_t)(jt)*64; \
        ldsload16(s_, d_); ldsload16(s_ + 32, d_ + 8192); }
#define STG_B(bs, h, jt) { char* d_ = smem + (bs)*65536 + 32768 + (h)*16384 + (w << 10) + (lane << 4); \
        const h16* s_ = gB + (size_t)((h)*128) * ldb + (size_t)(jt)*64; \
        ldsload16(s_, d_); ldsload16(s_ + 32, d_ + 8192); }
#define MFMA16(mp, AF) { \
        __builtin_amdgcn_s_setprio(1); \
        _Pragma("unroll") for (int i = 0; i < 2; ++i) \
        _Pragma("unroll") for (int n = 0; n < 4; ++n) \
        _Pragma("unroll") for (int kk = 0; kk < 2; ++kk) \
            acc[(mp)*2 + i][n] = __builtin_amdgcn_mfma_f32_16x16x32_f16(AF[i][kk], bf[n][kk], acc[(mp)*2 + i][n], 0, 0, 0); \
        __builtin_amdgcn_s_setprio(0); SB0 }

    STG_A(0, 0, 0) STG_A(0, 1, 0) STG_B(0, 0, 0) STG_B(0, 1, 0)

    int cur = 0;
    for (int j = 0; j < nt; ++j) {
        const int nxt = cur ^ 1;
        if (j + 1 < nt) {
            STG_A(nxt, 0, j + 1)
            asm volatile("s_waitcnt vmcnt(2)" ::: "memory");
        } else {
            asm volatile("s_waitcnt vmcnt(0)" ::: "memory");
        }
        SB0
        __builtin_amdgcn_s_barrier();
        SB0
        const char* Ab = smem + cur * 65536 + wr * 16384;
        const char* Bb = smem + cur * 65536 + 32768 + (wc >> 1) * 16384;
        h16x8 bf[4][2];
#pragma unroll
        for (int n = 0; n < 4; ++n)
#pragma unroll
            for (int kk = 0; kk < 2; ++kk)
                bf[n][kk] = *(const h16x8*)(Bb + kk * 8192 + (((wc & 1) << 2) + n) * 1024 + (lane << 4));
        h16x8 a0[2][2];
#pragma unroll
        for (int i = 0; i < 2; ++i)
#pragma unroll
            for (int kk = 0; kk < 2; ++kk)
                a0[i][kk] = *(const h16x8*)(Ab + kk * 8192 + (0 + i) * 1024 + (lane << 4));
        asm volatile("s_waitcnt lgkmcnt(0)" ::: "memory");
        SB0
        MFMA16(0, a0)
        h16x8 a1[2][2];
#pragma unroll
        for (int i = 0; i < 2; ++i)
#pragma unroll
            for (int kk = 0; kk < 2; ++kk)
                a1[i][kk] = *(const h16x8*)(Ab + kk * 8192 + (2 + i) * 1024 + (lane << 4));
        if (j + 1 < nt) STG_A(nxt, 1, j + 1)
        asm volatile("s_waitcnt lgkmcnt(0)" ::: "memory");
        SB0
        __builtin_amdgcn_s_barrier();
        SB0
        MFMA16(1, a1)
        h16x8 a2[2][2];
#pragma unroll
        for (int i = 0; i < 2; ++i)
#pragma unroll
            for (int kk = 0; kk < 2; ++kk)
                a2[i][kk] = *(const h16x8*)(Ab + kk * 8192 + (4 + i) * 1024 + (lane << 4));
        if (j + 1 < nt) STG_B(nxt, 0, j + 1)
        asm volatile("s_waitcnt lgkmcnt(0)" ::: "memory");
        SB0
        __builtin_amdgcn_s_barrier();
        SB0
        MFMA16(2, a2)
        h16x8 a3[2][2];
#pragma unroll
        for (int i = 0; i < 2; ++i)
#pragma unroll
            for (int kk = 0; kk < 2; ++kk)
                a3[i][kk] = *(const h16x8*)(Ab + kk * 8192 + (6 + i) * 1024 + (lane << 4));
        if (j + 1 < nt) STG_B(nxt, 1, j + 1)
        asm volatile("s_waitcnt lgkmcnt(0)" ::: "memory");
        SB0
        __builtin_amdgcn_s_barrier();
        SB0
        MFMA16(3, a3)
        cur = nxt;
    }
#undef MFMA16
#undef STG_A
#undef STG_B
#undef SB0

    float bv[4];
#pragma unroll
    for (int n = 0; n < 4; ++n)
        bv[n] = bias ? bias[col0 + (wc << 6) + n * 16 + rr] : 0.f;
#pragma unroll
    for (int m = 0; m < 8; ++m) {
        size_t rbase = row0 + (wr << 7) + m * 16 + (kc << 2);
#pragma unroll
        for (int jj = 0; jj < 4; ++jj) {
            h16* rowp = C + (rbase + jj) * (size_t)ldc + col0 + (wc << 6) + rr;
#pragma unroll
            for (int n = 0; n < 4; ++n) {
                float v = acc[m][n][jj] + bv[n];
                if (MODE == 1) v = fmaxf(v, 0.f);
                rowp[n * 16] = (h16)v;
            }
        }
    }
}

// ---------------------------------------------------------------- 4-phase 256x128 GEMM (R12-proven schedule; R17: MODE epilogue)
// MODE: 0 = +bias (full K), 1 = +bias+relu, 3 = split-K partial (out at z*M*N)
template<int MODE>
__global__ __launch_bounds__(512, 2) void k_g8n(
        const h16* __restrict__ A, int lda,
        const h16* __restrict__ B, int ldb,
        const float* __restrict__ bias,
        h16* __restrict__ C, int ldc,
        int M, int N, int Keff) {
    __shared__ char smem[98304];
    const int t = threadIdx.x;
    const int w = t >> 6, lane = t & 63;
    const int wr = w >> 1, wc = w & 1;
    const int kc = lane >> 4, rr = lane & 15;
    int bx, by;
    xcd_swz(bx, by);
    const size_t row0 = (size_t)by * 256;
    const size_t col0 = (size_t)bx * 128;
    const int z = blockIdx.z;

    const h16* gA = A + (size_t)z * Keff + (row0 + (w << 4) + rr) * (size_t)lda + (kc << 3);
    const h16* gB = B + (size_t)z * Keff + (col0 + (w << 4) + rr) * (size_t)ldb + (kc << 3);
    h16* Cz = C + (MODE == 3 ? (size_t)z * (size_t)M * N : (size_t)0);

    f32x4 acc[4][4];
#pragma unroll
    for (int m = 0; m < 4; ++m)
#pragma unroll
        for (int n = 0; n < 4; ++n) acc[m][n] = (f32x4){0.f, 0.f, 0.f, 0.f};

    const int nt = Keff >> 6;

#define SB0 __builtin_amdgcn_sched_barrier(0);
#define STG_A(bs, h, jt) { char* d_ = smem + (bs)*49152 + (h)*16384 + (w << 10) + (lane << 4); \
        const h16* s_ = gA + (size_t)((h)*128) * lda + (size_t)(jt)*64; \
        ldsload16(s_, d_); ldsload16(s_ + 32, d_ + 8192); }
#define STG_B(bs, jt) { char* d_ = smem + (bs)*49152 + 32768 + (w << 10) + (lane << 4); \
        const h16* s_ = gB + (size_t)(jt)*64; \
        ldsload16(s_, d_); ldsload16(s_ + 32, d_ + 8192); }
#define MFMA8(mp, AF) { \
        __builtin_amdgcn_s_setprio(1); \
        _Pragma("unroll") for (int n = 0; n < 4; ++n) \
        _Pragma("unroll") for (int kk = 0; kk < 2; ++kk) \
            acc[mp][n] = __builtin_amdgcn_mfma_f32_16x16x32_f16(AF[kk], bf[n][kk], acc[mp][n], 0, 0, 0); \
        __builtin_amdgcn_s_setprio(0); SB0 }
#define LDA_FRAG(dst, mp) { int g_ = (wr << 2) + (mp); \
        const char* p_ = smem + cur * 49152 + ((g_ >> 3) << 14) + ((g_ & 7) << 10) + (lane << 4); \
        _Pragma("unroll") for (int kk = 0; kk < 2; ++kk) \
            dst[kk] = *(const h16x8*)(p_ + kk * 8192); }

    STG_A(0, 0, 0) STG_A(0, 1, 0) STG_B(0, 0)

    int cur = 0;
    for (int j = 0; j < nt; ++j) {
        const int nxt = cur ^ 1;
        if (j + 1 < nt) {
            STG_A(nxt, 0, j + 1)
            asm volatile("s_waitcnt vmcnt(2)" ::: "memory");
        } else {
            asm volatile("s_waitcnt vmcnt(0)" ::: "memory");
        }
        SB0
        __builtin_amdgcn_s_barrier();
        SB0
        const char* Bb = smem + cur * 49152 + 32768;
        h16x8 bf[4][2];
#pragma unroll
        for (int n = 0; n < 4; ++n)
#pragma unroll
            for (int kk = 0; kk < 2; ++kk)
                bf[n][kk] = *(const h16x8*)(Bb + kk * 8192 + (((wc << 2) + n) << 10) + (lane << 4));
        h16x8 a0[2];
        LDA_FRAG(a0, 0)
        asm volatile("s_waitcnt lgkmcnt(0)" ::: "memory");
        SB0
        MFMA8(0, a0)
        h16x8 a1[2];
        LDA_FRAG(a1, 1)
        if (j + 1 < nt) STG_A(nxt, 1, j + 1)
        asm volatile("s_waitcnt lgkmcnt(0)" ::: "memory");
        SB0
        __builtin_amdgcn_s_barrier();
        SB0
        MFMA8(1, a1)
        h16x8 a2[2];
        LDA_FRAG(a2, 2)
        if (j + 1 < nt) STG_B(nxt, j + 1)
        asm volatile("s_waitcnt lgkmcnt(0)" ::: "memory");
        SB0
        __builtin_amdgcn_s_barrier();
        SB0
        MFMA8(2, a2)
        h16x8 a3[2];
        LDA_FRAG(a3, 3)
        asm volatile("s_waitcnt lgkmcnt(0)" ::: "memory");
        SB0
        __builtin_amdgcn_s_barrier();
        SB0
        MFMA8(3, a3)
        cur = nxt;
    }
#undef LDA_FRAG
#undef MFMA8
#undef STG_A
#undef STG_B
#undef SB0

    float bv[4];
#pragma unroll
    for (int n = 0; n < 4; ++n)
        bv[n] = (MODE == 0 || MODE == 1) ? bias[col0 + (wc << 6) + n * 16 + rr] : 0.f;
#pragma unroll
    for (int m = 0; m < 4; ++m) {
        size_t rbase = row0 + (wr << 6) + m * 16 + (kc << 2);
#pragma unroll
        for (int jj = 0; jj < 4; ++jj) {
            h16* rowp = Cz + (rbase + jj) * (size_t)ldc + col0 + (wc << 6) + rr;
#pragma unroll
            for (int n = 0; n < 4; ++n) {
                float v = acc[m][n][jj] + bv[n];
                if (MODE == 1) v = fmaxf(v, 0.f);
                rowp[n * 16] = (h16)v;
            }
        }
    }
}

// ---------------------------------------------------------------- 128x128 2-phase GEMM (R7-proven; DOTS)
template<int MODE>
__global__ __launch_bounds__(512, 4) void k_hgemm(
        const h16* __restrict__ A, int lda,
        const h16* __restrict__ B, int ldb,
        const float* __restrict__ bias,
        h16* __restrict__ C, int ldc,
        int M, int N, int Keff) {
    __shared__ char smem[49152];
    const int t = threadIdx.x;
    const int w = t >> 6, lane = t & 63;
    const int wr = w >> 2, wc = w & 3;
    const int kc = lane >> 4, rr = lane & 15;
    int bx, by;
    xcd_swz(bx, by);
    const size_t row0 = (size_t)by * 128;
    const size_t col0 = (size_t)bx * 128;

    const h16* gA = A + (row0 + (w << 4) + rr) * (size_t)lda + (kc << 3);
    const h16* gB = B + (col0 + (w << 4) + rr) * (size_t)ldb + (kc << 3);

    f32x4 acc[4][2];
#pragma unroll
    for (int m = 0; m < 4; ++m)
#pragma unroll
        for (int n = 0; n < 2; ++n) acc[m][n] = (f32x4){0.f, 0.f, 0.f, 0.f};

    const int nt = Keff >> 5;

#define SB0 __builtin_amdgcn_sched_barrier(0);
#define STAGE(step, slot) { char* sA_ = smem + ((slot) << 14) + (w << 10); \
        ldsload16(gA + (size_t)(step) * 32, sA_); \
        ldsload16(gB + (size_t)(step) * 32, sA_ + 8192); }
#define KSTEP(WAITLIT, slotR, DOSTAGE, stepW, slotW) { \
        asm volatile("s_waitcnt vmcnt(" WAITLIT ")" ::: "memory"); \
        SB0 \
        __builtin_amdgcn_s_barrier(); \
        SB0 \
        const char* bA = smem + ((slotR) << 14); \
        const char* bB = bA + 8192; \
        h16x8 af[4], bf[2]; \
        _Pragma("unroll") for (int m = 0; m < 4; ++m) \
            af[m] = *(const h16x8*)(bA + ((wr << 2) + m) * 1024 + lane * 16); \
        _Pragma("unroll") for (int n = 0; n < 2; ++n) \
            bf[n] = *(const h16x8*)(bB + ((wc << 1) + n) * 1024 + lane * 16); \
        asm volatile("s_waitcnt lgkmcnt(0)" ::: "memory"); \
        SB0 \
        if (DOSTAGE) STAGE(stepW, slotW) \
        __builtin_amdgcn_s_setprio(1); \
        _Pragma("unroll") for (int m = 0; m < 4; ++m) \
        _Pragma("unroll") for (int n = 0; n < 2; ++n) \
            acc[m][n] = __builtin_amdgcn_mfma_f32_16x16x32_f16(af[m], bf[n], acc[m][n], 0, 0, 0); \
        __builtin_amdgcn_s_setprio(0); \
        SB0 }

    STAGE(0, 0) STAGE(1, 1)
    int slotR = 0, slotW = 2;
    int it = 0;
    for (; it < nt - 2; ++it) {
        KSTEP("2", slotR, 1, it + 2, slotW)
        slotR = (slotR == 2) ? 0 : slotR + 1;
        slotW = (slotW == 2) ? 0 : slotW + 1;
    }
    KSTEP("2", slotR, 0, 0, 0)
    slotR = (slotR == 2) ? 0 : slotR + 1;
    KSTEP("0", slotR, 0, 0, 0)
#undef KSTEP
#undef STAGE
#undef SB0

#pragma unroll
    for (int n = 0; n < 2; ++n) {
        size_t col = col0 + (wc << 5) + n * 16 + rr;
#pragma unroll
        for (int m = 0; m < 4; ++m) {
            size_t rbase = row0 + (wr << 6) + m * 16 + (kc << 2);
#pragma unroll
            for (int j = 0; j < 4; ++j)
                C[(rbase + j) * (size_t)ldc + col] = (h16)acc[m][n][j];
        }
    }
}

// ---------------------------------------------------------------- fused attention + O-proj + residual + LN (R13/R16-proven)
__global__ __launch_bounds__(512, 1) void k_fattn(
        const h16* __restrict__ QKV,
        const h16* __restrict__ Wo,
        const float* __restrict__ bo,
        h16* __restrict__ X,
        const float* __restrict__ lw,
        const float* __restrict__ lb) {
    __shared__ char smem[131072];
    const int t = threadIdx.x;
    const int w = t >> 6, lane = t & 63;
    const int rr = lane & 15, kc = lane >> 4;
    const size_t b = (size_t)(((blockIdx.x & 7) << 5) + (blockIdx.x >> 3));
    const size_t row0 = b * 32;
    const h16* qkv = QKV + row0 * 1536;

#define SB0 __builtin_amdgcn_sched_barrier(0);
#pragma unroll
    for (int mat = 0; mat < 3; ++mat)
#pragma unroll
        for (int g = 0; g < 2; ++g)
#pragma unroll
            for (int q = 0; q < 2; ++q) {
                const h16* src = qkv + (size_t)(g * 16 + rr) * 1536 + mat * 512 + w * 64 + q * 32 + kc * 8;
                ldsload16(src, smem + w * 12288 + mat * 4096 + (g * 2 + q) * 1024 + lane * 16);
            }
    asm volatile("s_waitcnt vmcnt(4)" ::: "memory");
    SB0

    const char* Qb = smem + w * 12288;
    const char* Kb = Qb + 4096;
    f32x4 s[2][2];
#pragma unroll
    for (int m = 0; m < 2; ++m)
#pragma unroll
        for (int n = 0; n < 2; ++n) s[m][n] = (f32x4){0.f, 0.f, 0.f, 0.f};
#pragma unroll
    for (int q = 0; q < 2; ++q) {
        h16x8 aq[2], bk[2];
#pragma unroll
        for (int m = 0; m < 2; ++m) aq[m] = *(const h16x8*)(Qb + (m * 2 + q) * 1024 + lane * 16);
#pragma unroll
        for (int n = 0; n < 2; ++n) bk[n] = *(const h16x8*)(Kb + (n * 2 + q) * 1024 + lane * 16);
#pragma unroll
        for (int m = 0; m < 2; ++m)
#pragma unroll
            for (int n = 0; n < 2; ++n)
                s[m][n] = __builtin_amdgcn_mfma_f32_16x16x32_f16(aq[m], bk[n], s[m][n], 0, 0, 0);
    }

    float p[2][2][4];
#pragma unroll
    for (int m = 0; m < 2; ++m)
#pragma unroll
        for (int j = 0; j < 4; ++j) {
            float a0 = s[m][0][j] * 0.125f, a1 = s[m][1][j] * 0.125f;
            float mx = fmaxf(a0, a1);
            mx = fmaxf(mx, __shfl_xor(mx, 1));
            mx = fmaxf(mx, __shfl_xor(mx, 2));
            mx = fmaxf(mx, __shfl_xor(mx, 4));
            mx = fmaxf(mx, __shfl_xor(mx, 8));
            float e0 = __expf(a0 - mx), e1 = __expf(a1 - mx);
            float sm = e0 + e1;
            sm += __shfl_xor(sm, 1);
            sm += __shfl_xor(sm, 2);
            sm += __shfl_xor(sm, 4);
            sm += __shfl_xor(sm, 8);
            float inv = 1.f / sm;
            p[m][0][j] = e0 * inv;
            p[m][1][j] = e1 * inv;
        }

    char* Pb = smem + 98304 + w * 2048;
#pragma unroll
    for (int m = 0; m < 2; ++m)
#pragma unroll
        for (int n = 0; n < 2; ++n)
#pragma unroll
            for (int j = 0; j < 4; ++j)
                *(h16*)(Pb + m * 1024 + (kc * 4 + j + ((n * 2 + (rr >> 3)) & 3) * 16) * 16 + (lane & 7) * 2) = (h16)p[m][n][j];
    asm volatile("s_waitcnt lgkmcnt(0)" ::: "memory");
    SB0
    h16x8 ap[2];
#pragma unroll
    for (int m = 0; m < 2; ++m) ap[m] = *(const h16x8*)(Pb + m * 1024 + lane * 16);

    asm volatile("s_waitcnt vmcnt(0)" ::: "memory");
    SB0

    const char* Vb = Qb + 8192;
    f32x4 o[2][4];
#pragma unroll
    for (int m = 0; m < 2; ++m)
#pragma unroll
        for (int n = 0; n < 4; ++n) o[m][n] = (f32x4){0.f, 0.f, 0.f, 0.f};
#pragma unroll
    for (int n = 0; n < 4; ++n) {
        h16x8 bv;
#pragma unroll
        for (int e = 0; e < 8; ++e)
            bv[e] = *(const h16*)(Vb + ((kc >> 1) * 2 + (n >> 1)) * 1024
                                  + ((kc & 1) * 8 + e) * 16
                                  + ((n * 2 + (rr >> 3)) & 3) * 256 + (lane & 7) * 2);
#pragma unroll
        for (int m = 0; m < 2; ++m)
            o[m][n] = __builtin_amdgcn_mfma_f32_16x16x32_f16(ap[m], bv, o[m][n], 0, 0, 0);
    }

#pragma unroll
    for (int m = 0; m < 2; ++m)
#pragma unroll
        for (int n = 0; n < 4; ++n)
#pragma unroll
            for (int j = 0; j < 4; ++j)
                *(h16*)(smem + 98304 + (m * 16 + w * 2 + (n >> 1)) * 1024
                        + (kc * 4 + j + ((n & 1) * 2 + (rr >> 3)) * 16) * 16 + (lane & 7) * 2) = (h16)o[m][n][j];
    asm volatile("s_waitcnt lgkmcnt(0)" ::: "memory");
    SB0
    __builtin_amdgcn_s_barrier();
    SB0

    f32x4 acc[2][4];
#pragma unroll
    for (int m = 0; m < 2; ++m)
#pragma unroll
        for (int n = 0; n < 4; ++n) acc[m][n] = (f32x4){0.f, 0.f, 0.f, 0.f};

#define STGB(js, sl) { _Pragma("unroll") for (int u = 0; u < 4; ++u) { \
        const h16* s_ = Wo + (size_t)((((u << 3) + w) << 4) + rr) * DM + (js) * 32 + (kc << 3); \
        ldsload16(s_, smem + (sl) * 32768 + (((u << 3) + w) << 10) + (lane << 4)); } }

    STGB(0, 0) STGB(1, 1)
    int slotR = 0, slotW = 2;
    for (int sx = 0; sx < 15; ++sx) {
        asm volatile("s_waitcnt vmcnt(4)" ::: "memory");
        SB0
        __builtin_amdgcn_s_barrier();
        SB0
        h16x8 af[2], bf[4];
#pragma unroll
        for (int m = 0; m < 2; ++m)
            af[m] = *(const h16x8*)(smem + 98304 + (m * 16 + sx) * 1024 + (lane << 4));
#pragma unroll
        for (int n = 0; n < 4; ++n)
            bf[n] = *(const h16x8*)(smem + slotR * 32768 + (((w << 2) + n) << 10) + (lane << 4));
        asm volatile("s_waitcnt lgkmcnt(0)" ::: "memory");
        SB0
        if (sx + 2 < 16) STGB(sx + 2, slotW)
        __builtin_amdgcn_s_setprio(1);
#pragma unroll
        for (int m = 0; m < 2; ++m)
#pragma unroll
            for (int n = 0; n < 4; ++n)
                acc[m][n] = __builtin_amdgcn_mfma_f32_16x16x32_f16(af[m], bf[n], acc[m][n], 0, 0, 0);
        __builtin_amdgcn_s_setprio(0);
        SB0
        slotR = (slotR == 2) ? 0 : slotR + 1;
        slotW = (slotW == 2) ? 0 : slotW + 1;
    }
    {
        asm volatile("s_waitcnt vmcnt(0)" ::: "memory");
        SB0
        __builtin_amdgcn_s_barrier();
        SB0
        h16x8 af[2], bf[4];
#pragma unroll
        for (int m = 0; m < 2; ++m)
            af[m] = *(const h16x8*)(smem + 98304 + (m * 16 + 15) * 1024 + (lane << 4));
#pragma unroll
        for (int n = 0; n < 4; ++n)
            bf[n] = *(const h16x8*)(smem + slotR * 32768 + (((w << 2) + n) << 10) + (lane << 4));
        asm volatile("s_waitcnt lgkmcnt(0)" ::: "memory");
        SB0
#pragma unroll
        for (int m = 0; m < 2; ++m)
#pragma unroll
            for (int n = 0; n < 4; ++n)
                acc[m][n] = __builtin_amdgcn_mfma_f32_16x16x32_f16(af[m], bf[n], acc[m][n], 0, 0, 0);
    }
#undef STGB
#undef SB0
    __syncthreads();

    float* outl = (float*)smem;
    float bvv[4];
#pragma unroll
    for (int n = 0; n < 4; ++n)
        bvv[n] = bo[(w << 6) + n * 16 + rr];
#pragma unroll
    for (int m = 0; m < 2; ++m)
#pragma unroll
        for (int n = 0; n < 4; ++n)
#pragma unroll
            for (int j = 0; j < 4; ++j) {
                int r = m * 16 + kc * 4 + j;
                int c = (w << 6) + n * 16 + rr;
                outl[r * 516 + c] = acc[m][n][j] + bvv[n];
            }
    __syncthreads();
    {
        const int r = t >> 4, l = t & 15;
        const size_t grow = (row0 + r) * (size_t)DM;
        float v[32];
        float sum = 0.f, sq = 0.f;
#pragma unroll
        for (int i = 0; i < 32; ++i) {
            int col = l + (i << 4);
            float vv = outl[r * 516 + col] + (float)X[grow + col];
            v[i] = vv;
            sum += vv;
            sq += vv * vv;
        }
#pragma unroll
        for (int o2 = 8; o2; o2 >>= 1) {
            sum += __shfl_xor(sum, o2);
            sq  += __shfl_xor(sq, o2);
        }
        float mean = sum * (1.f / 512.f);
        float var = sq * (1.f / 512.f) - mean * mean;
        float inv = 1.f / sqrtf(var + 1e-5f);
#pragma unroll
        for (int i = 0; i < 32; ++i) {
            int col = l + (i << 4);
            X[grow + col] = (h16)((v[i] - mean) * inv * lw[col] + lb[col]);
        }
    }
}

// ---------------------------------------------------------------- x = LN(x + p0 + p1 + bias)*w + b (XCD-aligned rows)
__global__ __launch_bounds__(256) void k_addln_red(h16* __restrict__ x,
                                                   const h16* __restrict__ p0,
                                                   const h16* __restrict__ p1,
                                                   const float* __restrict__ bias,
                                                   const float* __restrict__ w,
                                                   const float* __restrict__ b) {
    size_t row = (size_t)(((blockIdx.x & 7) << 10) + (blockIdx.x >> 3));
    int t = threadIdx.x;
    size_t o0 = row * DM + t, o1 = o0 + 256;
    float v0 = (float)x[o0] + (float)p0[o0] + (float)p1[o0] + bias[t];
    float v1 = (float)x[o1] + (float)p0[o1] + (float)p1[o1] + bias[t + 256];
    float s = v0 + v1;
#pragma unroll
    for (int o = 32; o; o >>= 1) s += __shfl_xor(s, o);
    __shared__ float ss[4], qs[4];
    if ((t & 63) == 0) ss[t >> 6] = s;
    __syncthreads();
    float mean = (ss[0] + ss[1] + ss[2] + ss[3]) * (1.f / 512.f);
    float d0 = v0 - mean, d1 = v1 - mean;
    float qv = d0 * d0 + d1 * d1;
#pragma unroll
    for (int o = 32; o; o >>= 1) qv += __shfl_xor(qv, o);
    if ((t & 63) == 0) qs[t >> 6] = qv;
    __syncthreads();
    float var = (qs[0] + qs[1] + qs[2] + qs[3]) * (1.f / 512.f);
    float inv = 1.f / sqrtf(var + 1e-5f);
    x[o0] = (h16)(d0 * inv * w[t] + b[t]);
    x[o1] = (h16)(d1 * inv * w[t + 256] + b[t + 256]);
}

// ---------------------------------------------------------------- l2 rows: f32 in -> f16 out
__global__ __launch_bounds__(256) void k_l2rows_h(const float* __restrict__ in,
                                                  h16* __restrict__ outp) {
    size_t row = blockIdx.x;
    int t = threadIdx.x;
    float v0 = in[row * DM + t], v1 = in[row * DM + t + 256];
    float q = v0 * v0 + v1 * v1;
#pragma unroll
    for (int o = 32; o; o >>= 1) q += __shfl_xor(q, o);
    __shared__ float qs[4];
    if ((t & 63) == 0) qs[t >> 6] = q;
    __syncthreads();
    float n = sqrtf(qs[0] + qs[1] + qs[2] + qs[3]);
    float sc = 1.f / fmaxf(n, 1e-12f);
    outp[row * DM + t]       = (h16)(v0 * sc);
    outp[row * DM + t + 256] = (h16)(v1 * sc);
}

// ---------------------------------------------------------------- TOK rows (l2'd frames + video tokens)
__global__ __launch_bounds__(256) void k_build_tok_h(const float* __restrict__ frames,
                                                     const h16* __restrict__ X,
                                                     h16* __restrict__ TOK) {
    int rid = blockIdx.x;
    int j = rid / NTOK_V, tt = rid % NTOK_V;
    int t = threadIdx.x;
    float v0, v1;
    if (tt < 30) {
        const float* src = frames + ((size_t)j * 30 + tt) * DM;
        v0 = src[t]; v1 = src[t + 256];
    } else {
        const h16* src = X + ((size_t)j * 32 + (tt - 30)) * DM;
        v0 = (float)src[t]; v1 = (float)src[t + 256];
    }
    float q = v0 * v0 + v1 * v1;
#pragma unroll
    for (int o = 32; o; o >>= 1) q += __shfl_xor(q, o);
    __shared__ float qs[4];
    if ((t & 63) == 0) qs[t >> 6] = q;
    __syncthreads();
    float n = sqrtf(qs[0] + qs[1] + qs[2] + qs[3]);
    float sc = 1.f / fmaxf(n, 1e-12f);
    TOK[(size_t)rid * DM + t]       = (h16)(v0 * sc);
    TOK[(size_t)rid * DM + t + 256] = (h16)(v1 * sc);
}

// ---------------------------------------------------------------- max-reduce dots -> sims
__global__ __launch_bounds__(256) void k_sim_h(const h16* __restrict__ dots,
                                               float* __restrict__ out) {
    int i = blockIdx.x;
    int j = threadIdx.x;
    const h16* p = dots + (size_t)i * 15872 + (size_t)j * NTOK_V;
    float mf = -1e30f, mv = -1e30f;
#pragma unroll
    for (int tt = 0; tt < 30; ++tt) mf = fmaxf(mf, (float)p[tt]);
#pragma unroll
    for (int tt = 30; tt < 62; ++tt) mv = fmaxf(mv, (float)p[tt]);
    int o = i * 256 + j;
    out[o]          = mf + mv;
    out[65536 + o]  = mf;
    out[131072 + o] = mv;
}

// ---------------------------------------------------------------- launcher
extern "C" void kernel_launch(void* const* d_in, const int* in_sizes, int n_in,
                              void* d_out, int out_size, void* d_ws, size_t ws_size,
                              hipStream_t stream) {
    const float* text   = (const float*)d_in[0];
    const float* frames = (const float*)d_in[1];
    const float* expt   = (const float*)d_in[2];
    const float* Wqkv   = (const float*)d_in[3];
    const float* bqkv   = (const float*)d_in[4];
    const float* Wo     = (const float*)d_in[5];
    const float* bo     = (const float*)d_in[6];
    const float* ln1w   = (const float*)d_in[7];
    const float* ln1b   = (const float*)d_in[8];
    const float* W1     = (const float*)d_in[9];
    const float* b1     = (const float*)d_in[10];
    const float* W2     = (const float*)d_in[11];
    const float* b2     = (const float*)d_in[12];
    const float* ln2w   = (const float*)d_in[13];
    const float* ln2b   = (const float*)d_in[14];
    float* out = (float*)d_out;

    char* wsb = (char*)d_ws;
    const size_t MB = 1024 * 1024;
    h16* Xh    = (h16*)(wsb);              // 8 MB   [8192,512]
    h16* P0    = (h16*)(wsb + 8 * MB);     // 8 MB   split-K partial 0 (FF2)
    h16* P1    = (h16*)(wsb + 16 * MB);    // 8 MB   split-K partial 1
    h16* FFh   = (h16*)(wsb + 32 * MB);    // 32 MB  [8192,2048] (also QKV [8192,1536])
    h16* TOKh  = (h16*)(wsb + 32 * MB);    // alias FF (post-transformer)
    h16* DOTSh = (h16*)(wsb + 48 * MB);    // alias FF tail
    h16* Wh    = (h16*)(wsb + 64 * MB);    // 25 MB  all weights fp16 (contiguous)
    h16* QHATh = (h16*)(wsb + 90 * MB);    // 0.25 MB

    h16* Whqkv = Wh;                       // 4*1536*512
    h16* Who   = Whqkv + 3145728;          // 4*512*512
    h16* Wh1   = Who + 1048576;            // 4*2048*512
    h16* Wh2   = Wh1 + 4194304;            // 4*2048*512

    k_cvt_all<<<6144, 256, 0, stream>>>(Wqkv, Wo, W1, W2, Wh);
    k_concat_h<<<8192, 256, 0, stream>>>(frames, expt, Xh);

    for (int l = 0; l < 4; ++l) {
        const h16* Wqkv_l = Whqkv + (size_t)l * 786432;
        const h16* Wo_l   = Who   + (size_t)l * 262144;
        const h16* W1_l   = Wh1   + (size_t)l * 1048576;
        const h16* W2_l   = Wh2   + (size_t)l * 1048576;

        k_g8n<0><<<dim3(12, 32, 1), 512, 0, stream>>>(
            Xh, 512, Wqkv_l, 512, bqkv + (size_t)l * 1536, FFh, 1536, 8192, 1536, 512);
        k_fattn<<<256, 512, 0, stream>>>(FFh, Wo_l, bo + (size_t)l * 512, Xh,
                                         ln1w + (size_t)l * 512, ln1b + (size_t)l * 512);
        k_g8<1><<<dim3(8, 32, 1), 512, 0, stream>>>(
            Xh, 512, W1_l, 512, b1 + (size_t)l * 2048, FFh, 2048, 8192, 2048, 512);
        k_g8n<3><<<dim3(4, 32, 2), 512, 0, stream>>>(
            FFh, 2048, W2_l, 2048, nullptr, P0, 512, 8192, 512, 1024);
        k_addln_red<<<8192, 256, 0, stream>>>(Xh, P0, P1, b2 + (size_t)l * 512,
                                              ln2w + (size_t)l * 512, ln2b + (size_t)l * 512);
    }

    k_l2rows_h<<<256, 256, 0, stream>>>(text, QHATh);
    k_build_tok_h<<<256 * NTOK_V, 256, 0, stream>>>(frames, Xh, TOKh);
    k_hgemm<2><<<dim3(124, 2, 1), 512, 0, stream>>>(
        QHATh, 512, TOKh, 512, nullptr, DOTSh, 15872, 256, 15872, 512);
    k_sim_h<<<256, 256, 0, stream>>>(DOTSh, out);
}

// Round 18
// 500.558 us; speedup vs baseline: 1.0527x; 1.0527x over previous
//
#include <hip/hip_runtime.h>
#include <math.h>

#define DM 512
#define NTOK_V 62

typedef _Float16 h16;
typedef __attribute__((ext_vector_type(8))) _Float16 h16x8;
typedef __attribute__((ext_vector_type(4))) float f32x4;

__device__ __forceinline__ void ldsload16(const void* g, void* l) {
    __builtin_amdgcn_global_load_lds(
        (const __attribute__((address_space(1))) unsigned int*)g,
        (__attribute__((address_space(3))) unsigned int*)l, 16, 0, 0);
}

// XCD-chunked bijective blockIdx swizzle (T1; requires nwg%8==0 per z-plane).
// Scheme: XCD k owns token rows [k*1024,(k+1)*1024).
__device__ __forceinline__ void xcd_swz(int& bx, int& by) {
    const int gx = gridDim.x, gy = gridDim.y;
    const int lin = blockIdx.x + gx * blockIdx.y;
    const int cpx = (gx * gy) >> 3;
    const int wg = (lin & 7) * cpx + (lin >> 3);
    bx = wg % gx;
    by = wg / gx;
}

// ---------------------------------------------------------------- fused fp32 -> fp16 weight convert
__global__ __launch_bounds__(256) void k_cvt_all(const float* __restrict__ s0,
                                                 const float* __restrict__ s1,
                                                 const float* __restrict__ s2,
                                                 const float* __restrict__ s3,
                                                 h16* __restrict__ dst) {
    int i = blockIdx.x * 256 + threadIdx.x;
    const float* src;
    int off;
    if (i < 393216)       { src = s0; off = i; }
    else if (i < 524288)  { src = s1; off = i - 393216; }
    else if (i < 1048576) { src = s2; off = i - 524288; }
    else                  { src = s3; off = i - 1048576; }
    float4 a = ((const float4*)src)[off * 2];
    float4 b = ((const float4*)src)[off * 2 + 1];
    h16x8 h;
    h[0] = (h16)a.x; h[1] = (h16)a.y; h[2] = (h16)a.z; h[3] = (h16)a.w;
    h[4] = (h16)b.x; h[5] = (h16)b.y; h[6] = (h16)b.z; h[7] = (h16)b.w;
    ((h16x8*)dst)[i] = h;
}

// ---------------------------------------------------------------- concat -> fp16 X (XCD-aligned rows)
__global__ __launch_bounds__(256) void k_concat_h(const float* __restrict__ frames,
                                                  const float* __restrict__ expt,
                                                  h16* __restrict__ X) {
    int row = ((blockIdx.x & 7) << 10) + (blockIdx.x >> 3);
    int b = row >> 5, s = row & 31;
    int t = threadIdx.x;
    const float* src = (s < 30) ? (frames + ((size_t)(b * 30 + s)) * DM)
                                : (expt + (size_t)(s - 30) * DM);
    X[(size_t)row * DM + t]       = (h16)src[t];
    X[(size_t)row * DM + t + 256] = (h16)src[t + 256];
}

// ---------------------------------------------------------------- 8-phase 256x256 MFMA GEMM (R9/R10-proven)
template<int MODE>   // 0 = +bias, 1 = +bias+relu
__global__ __launch_bounds__(512, 2) void k_g8(
        const h16* __restrict__ A, int lda,
        const h16* __restrict__ B, int ldb,
        const float* __restrict__ bias,
        h16* __restrict__ C, int ldc,
        int M, int N, int Keff) {
    __shared__ char smem[131072];
    const int t = threadIdx.x;
    const int w = t >> 6, lane = t & 63;
    const int wr = w >> 2, wc = w & 3;
    const int kc = lane >> 4, rr = lane & 15;
    int bx, by;
    xcd_swz(bx, by);
    const size_t row0 = (size_t)by * 256;
    const size_t col0 = (size_t)bx * 256;

    const h16* gA = A + (row0 + (w << 4) + rr) * (size_t)lda + (kc << 3);
    const h16* gB = B + (col0 + (w << 4) + rr) * (size_t)ldb + (kc << 3);

    f32x4 acc[8][4];
#pragma unroll
    for (int m = 0; m < 8; ++m)
#pragma unroll
        for (int n = 0; n < 4; ++n) acc[m][n] = (f32x4){0.f, 0.f, 0.f, 0.f};

    const int nt = Keff >> 6;

#define SB0 __builtin_amdgcn_sched_barrier(0);
#define STG_A(bs, h, jt) { char* d_ = smem + (bs)*65536 + (h)*16384 + (w << 10) + (lane << 4); \
        const h16* s_ = gA + (size_t)((h)*128) * lda + (size_t)(jt)*64; \
        ldsload16(s_, d_); ldsload16(s_ + 32, d_ + 8192); }
#define STG_B(bs, h, jt) { char* d_ = smem + (bs)*65536 + 32768 + (h)*16384 + (w << 10) + (lane << 4); \
        const h16* s_ = gB + (size_t)((h)*128) * ldb + (size_t)(jt)*64; \
        ldsload16(s_, d_); ldsload16(s_ + 32, d_ + 8192); }
#define MFMA16(mp, AF) { \
        __builtin_amdgcn_s_setprio(1); \
        _Pragma("unroll") for (int i = 0; i < 2; ++i) \
        _Pragma("unroll") for (int n = 0; n < 4; ++n) \
        _Pragma("unroll") for (int kk = 0; kk < 2; ++kk) \
            acc[(mp)*2 + i][n] = __builtin_amdgcn_mfma_f32_16x16x32_f16(AF[i][kk], bf[n][kk], acc[(mp)*2 + i][n], 0, 0, 0); \
        __builtin_amdgcn_s_setprio(0); SB0 }

    STG_A(0, 0, 0) STG_A(0, 1, 0) STG_B(0, 0, 0) STG_B(0, 1, 0)

    int cur = 0;
    for (int j = 0; j < nt; ++j) {
        const int nxt = cur ^ 1;
        if (j + 1 < nt) {
            STG_A(nxt, 0, j + 1)
            asm volatile("s_waitcnt vmcnt(2)" ::: "memory");
        } else {
            asm volatile("s_waitcnt vmcnt(0)" ::: "memory");
        }
        SB0
        __builtin_amdgcn_s_barrier();
        SB0
        const char* Ab = smem + cur * 65536 + wr * 16384;
        const char* Bb = smem + cur * 65536 + 32768 + (wc >> 1) * 16384;
        h16x8 bf[4][2];
#pragma unroll
        for (int n = 0; n < 4; ++n)
#pragma unroll
            for (int kk = 0; kk < 2; ++kk)
                bf[n][kk] = *(const h16x8*)(Bb + kk * 8192 + (((wc & 1) << 2) + n) * 1024 + (lane << 4));
        h16x8 a0[2][2];
#pragma unroll
        for (int i = 0; i < 2; ++i)
#pragma unroll
            for (int kk = 0; kk < 2; ++kk)
                a0[i][kk] = *(const h16x8*)(Ab + kk * 8192 + (0 + i) * 1024 + (lane << 4));
        asm volatile("s_waitcnt lgkmcnt(0)" ::: "memory");
        SB0
        MFMA16(0, a0)
        h16x8 a1[2][2];
#pragma unroll
        for (int i = 0; i < 2; ++i)
#pragma unroll
            for (int kk = 0; kk < 2; ++kk)
                a1[i][kk] = *(const h16x8*)(Ab + kk * 8192 + (2 + i) * 1024 + (lane << 4));
        if (j + 1 < nt) STG_A(nxt, 1, j + 1)
        asm volatile("s_waitcnt lgkmcnt(0)" ::: "memory");
        SB0
        __builtin_amdgcn_s_barrier();
        SB0
        MFMA16(1, a1)
        h16x8 a2[2][2];
#pragma unroll
        for (int i = 0; i < 2; ++i)
#pragma unroll
            for (int kk = 0; kk < 2; ++kk)
                a2[i][kk] = *(const h16x8*)(Ab + kk * 8192 + (4 + i) * 1024 + (lane << 4));
        if (j + 1 < nt) STG_B(nxt, 0, j + 1)
        asm volatile("s_waitcnt lgkmcnt(0)" ::: "memory");
        SB0
        __builtin_amdgcn_s_barrier();
        SB0
        MFMA16(2, a2)
        h16x8 a3[2][2];
#pragma unroll
        for (int i = 0; i < 2; ++i)
#pragma unroll
            for (int kk = 0; kk < 2; ++kk)
                a3[i][kk] = *(const h16x8*)(Ab + kk * 8192 + (6 + i) * 1024 + (lane << 4));
        if (j + 1 < nt) STG_B(nxt, 1, j + 1)
        asm volatile("s_waitcnt lgkmcnt(0)" ::: "memory");
        SB0
        __builtin_amdgcn_s_barrier();
        SB0
        MFMA16(3, a3)
        cur = nxt;
    }
#undef MFMA16
#undef STG_A
#undef STG_B
#undef SB0

    float bv[4];
#pragma unroll
    for (int n = 0; n < 4; ++n)
        bv[n] = bias ? bias[col0 + (wc << 6) + n * 16 + rr] : 0.f;
#pragma unroll
    for (int m = 0; m < 8; ++m) {
        size_t rbase = row0 + (wr << 7) + m * 16 + (kc << 2);
#pragma unroll
        for (int jj = 0; jj < 4; ++jj) {
            h16* rowp = C + (rbase + jj) * (size_t)ldc + col0 + (wc << 6) + rr;
#pragma unroll
            for (int n = 0; n < 4; ++n) {
                float v = acc[m][n][jj] + bv[n];
                if (MODE == 1) v = fmaxf(v, 0.f);
                rowp[n * 16] = (h16)v;
            }
        }
    }
}

// ---------------------------------------------------------------- 4-phase 256x128 split-K GEMM (R12-proven; FF2 only)
__global__ __launch_bounds__(512, 2) void k_g8n(
        const h16* __restrict__ A, int lda,
        const h16* __restrict__ B, int ldb,
        h16* __restrict__ C, int ldc,
        int M, int N, int Keff) {
    __shared__ char smem[98304];
    const int t = threadIdx.x;
    const int w = t >> 6, lane = t & 63;
    const int wr = w >> 1, wc = w & 1;
    const int kc = lane >> 4, rr = lane & 15;
    int bx, by;
    xcd_swz(bx, by);
    const size_t row0 = (size_t)by * 256;
    const size_t col0 = (size_t)bx * 128;
    const int z = blockIdx.z;

    const h16* gA = A + (size_t)z * Keff + (row0 + (w << 4) + rr) * (size_t)lda + (kc << 3);
    const h16* gB = B + (size_t)z * Keff + (col0 + (w << 4) + rr) * (size_t)ldb + (kc << 3);
    h16* Cz = C + (size_t)z * (size_t)M * N;

    f32x4 acc[4][4];
#pragma unroll
    for (int m = 0; m < 4; ++m)
#pragma unroll
        for (int n = 0; n < 4; ++n) acc[m][n] = (f32x4){0.f, 0.f, 0.f, 0.f};

    const int nt = Keff >> 6;

#define SB0 __builtin_amdgcn_sched_barrier(0);
#define STG_A(bs, h, jt) { char* d_ = smem + (bs)*49152 + (h)*16384 + (w << 10) + (lane << 4); \
        const h16* s_ = gA + (size_t)((h)*128) * lda + (size_t)(jt)*64; \
        ldsload16(s_, d_); ldsload16(s_ + 32, d_ + 8192); }
#define STG_B(bs, jt) { char* d_ = smem + (bs)*49152 + 32768 + (w << 10) + (lane << 4); \
        const h16* s_ = gB + (size_t)(jt)*64; \
        ldsload16(s_, d_); ldsload16(s_ + 32, d_ + 8192); }
#define MFMA8(mp, AF) { \
        __builtin_amdgcn_s_setprio(1); \
        _Pragma("unroll") for (int n = 0; n < 4; ++n) \
        _Pragma("unroll") for (int kk = 0; kk < 2; ++kk) \
            acc[mp][n] = __builtin_amdgcn_mfma_f32_16x16x32_f16(AF[kk], bf[n][kk], acc[mp][n], 0, 0, 0); \
        __builtin_amdgcn_s_setprio(0); SB0 }
#define LDA_FRAG(dst, mp) { int g_ = (wr << 2) + (mp); \
        const char* p_ = smem + cur * 49152 + ((g_ >> 3) << 14) + ((g_ & 7) << 10) + (lane << 4); \
        _Pragma("unroll") for (int kk = 0; kk < 2; ++kk) \
            dst[kk] = *(const h16x8*)(p_ + kk * 8192); }

    STG_A(0, 0, 0) STG_A(0, 1, 0) STG_B(0, 0)

    int cur = 0;
    for (int j = 0; j < nt; ++j) {
        const int nxt = cur ^ 1;
        if (j + 1 < nt) {
            STG_A(nxt, 0, j + 1)
            asm volatile("s_waitcnt vmcnt(2)" ::: "memory");
        } else {
            asm volatile("s_waitcnt vmcnt(0)" ::: "memory");
        }
        SB0
        __builtin_amdgcn_s_barrier();
        SB0
        const char* Bb = smem + cur * 49152 + 32768;
        h16x8 bf[4][2];
#pragma unroll
        for (int n = 0; n < 4; ++n)
#pragma unroll
            for (int kk = 0; kk < 2; ++kk)
                bf[n][kk] = *(const h16x8*)(Bb + kk * 8192 + (((wc << 2) + n) << 10) + (lane << 4));
        h16x8 a0[2];
        LDA_FRAG(a0, 0)
        asm volatile("s_waitcnt lgkmcnt(0)" ::: "memory");
        SB0
        MFMA8(0, a0)
        h16x8 a1[2];
        LDA_FRAG(a1, 1)
        if (j + 1 < nt) STG_A(nxt, 1, j + 1)
        asm volatile("s_waitcnt lgkmcnt(0)" ::: "memory");
        SB0
        __builtin_amdgcn_s_barrier();
        SB0
        MFMA8(1, a1)
        h16x8 a2[2];
        LDA_FRAG(a2, 2)
        if (j + 1 < nt) STG_B(nxt, j + 1)
        asm volatile("s_waitcnt lgkmcnt(0)" ::: "memory");
        SB0
        __builtin_amdgcn_s_barrier();
        SB0
        MFMA8(2, a2)
        h16x8 a3[2];
        LDA_FRAG(a3, 3)
        asm volatile("s_waitcnt lgkmcnt(0)" ::: "memory");
        SB0
        __builtin_amdgcn_s_barrier();
        SB0
        MFMA8(3, a3)
        cur = nxt;
    }
#undef LDA_FRAG
#undef MFMA8
#undef STG_A
#undef STG_B
#undef SB0

#pragma unroll
    for (int m = 0; m < 4; ++m) {
        size_t rbase = row0 + (wr << 6) + m * 16 + (kc << 2);
#pragma unroll
        for (int jj = 0; jj < 4; ++jj) {
            h16* rowp = Cz + (rbase + jj) * (size_t)ldc + col0 + (wc << 6) + rr;
#pragma unroll
            for (int n = 0; n < 4; ++n)
                rowp[n * 16] = (h16)acc[m][n][jj];
        }
    }
}

// ---------------------------------------------------------------- 128x128 2-phase GEMM (R7-proven; DOTS)
template<int MODE>
__global__ __launch_bounds__(512, 4) void k_hgemm(
        const h16* __restrict__ A, int lda,
        const h16* __restrict__ B, int ldb,
        const float* __restrict__ bias,
        h16* __restrict__ C, int ldc,
        int M, int N, int Keff) {
    __shared__ char smem[49152];
    const int t = threadIdx.x;
    const int w = t >> 6, lane = t & 63;
    const int wr = w >> 2, wc = w & 3;
    const int kc = lane >> 4, rr = lane & 15;
    int bx, by;
    xcd_swz(bx, by);
    const size_t row0 = (size_t)by * 128;
    const size_t col0 = (size_t)bx * 128;

    const h16* gA = A + (row0 + (w << 4) + rr) * (size_t)lda + (kc << 3);
    const h16* gB = B + (col0 + (w << 4) + rr) * (size_t)ldb + (kc << 3);

    f32x4 acc[4][2];
#pragma unroll
    for (int m = 0; m < 4; ++m)
#pragma unroll
        for (int n = 0; n < 2; ++n) acc[m][n] = (f32x4){0.f, 0.f, 0.f, 0.f};

    const int nt = Keff >> 5;

#define SB0 __builtin_amdgcn_sched_barrier(0);
#define STAGE(step, slot) { char* sA_ = smem + ((slot) << 14) + (w << 10); \
        ldsload16(gA + (size_t)(step) * 32, sA_); \
        ldsload16(gB + (size_t)(step) * 32, sA_ + 8192); }
#define KSTEP(WAITLIT, slotR, DOSTAGE, stepW, slotW) { \
        asm volatile("s_waitcnt vmcnt(" WAITLIT ")" ::: "memory"); \
        SB0 \
        __builtin_amdgcn_s_barrier(); \
        SB0 \
        const char* bA = smem + ((slotR) << 14); \
        const char* bB = bA + 8192; \
        h16x8 af[4], bf[2]; \
        _Pragma("unroll") for (int m = 0; m < 4; ++m) \
            af[m] = *(const h16x8*)(bA + ((wr << 2) + m) * 1024 + lane * 16); \
        _Pragma("unroll") for (int n = 0; n < 2; ++n) \
            bf[n] = *(const h16x8*)(bB + ((wc << 1) + n) * 1024 + lane * 16); \
        asm volatile("s_waitcnt lgkmcnt(0)" ::: "memory"); \
        SB0 \
        if (DOSTAGE) STAGE(stepW, slotW) \
        __builtin_amdgcn_s_setprio(1); \
        _Pragma("unroll") for (int m = 0; m < 4; ++m) \
        _Pragma("unroll") for (int n = 0; n < 2; ++n) \
            acc[m][n] = __builtin_amdgcn_mfma_f32_16x16x32_f16(af[m], bf[n], acc[m][n], 0, 0, 0); \
        __builtin_amdgcn_s_setprio(0); \
        SB0 }

    STAGE(0, 0) STAGE(1, 1)
    int slotR = 0, slotW = 2;
    int it = 0;
    for (; it < nt - 2; ++it) {
        KSTEP("2", slotR, 1, it + 2, slotW)
        slotR = (slotR == 2) ? 0 : slotR + 1;
        slotW = (slotW == 2) ? 0 : slotW + 1;
    }
    KSTEP("2", slotR, 0, 0, 0)
    slotR = (slotR == 2) ? 0 : slotR + 1;
    KSTEP("0", slotR, 0, 0, 0)
#undef KSTEP
#undef STAGE
#undef SB0

#pragma unroll
    for (int n = 0; n < 2; ++n) {
        size_t col = col0 + (wc << 5) + n * 16 + rr;
#pragma unroll
        for (int m = 0; m < 4; ++m) {
            size_t rbase = row0 + (wr << 6) + m * 16 + (kc << 2);
#pragma unroll
            for (int j = 0; j < 4; ++j)
                C[(rbase + j) * (size_t)ldc + col] = (h16)acc[m][n][j];
        }
    }
}

// ---------------------------------------------------------------- fused attention + O-proj + residual + LN (R13/R16-proven)
__global__ __launch_bounds__(512, 1) void k_fattn(
        const h16* __restrict__ QKV,
        const h16* __restrict__ Wo,
        const float* __restrict__ bo,
        h16* __restrict__ X,
        const float* __restrict__ lw,
        const float* __restrict__ lb) {
    __shared__ char smem[131072];
    const int t = threadIdx.x;
    const int w = t >> 6, lane = t & 63;
    const int rr = lane & 15, kc = lane >> 4;
    const size_t b = (size_t)(((blockIdx.x & 7) << 5) + (blockIdx.x >> 3));
    const size_t row0 = b * 32;
    const h16* qkv = QKV + row0 * 1536;

#define SB0 __builtin_amdgcn_sched_barrier(0);
#pragma unroll
    for (int mat = 0; mat < 3; ++mat)
#pragma unroll
        for (int g = 0; g < 2; ++g)
#pragma unroll
            for (int q = 0; q < 2; ++q) {
                const h16* src = qkv + (size_t)(g * 16 + rr) * 1536 + mat * 512 + w * 64 + q * 32 + kc * 8;
                ldsload16(src, smem + w * 12288 + mat * 4096 + (g * 2 + q) * 1024 + lane * 16);
            }
    asm volatile("s_waitcnt vmcnt(4)" ::: "memory");
    SB0

    const char* Qb = smem + w * 12288;
    const char* Kb = Qb + 4096;
    f32x4 s[2][2];
#pragma unroll
    for (int m = 0; m < 2; ++m)
#pragma unroll
        for (int n = 0; n < 2; ++n) s[m][n] = (f32x4){0.f, 0.f, 0.f, 0.f};
#pragma unroll
    for (int q = 0; q < 2; ++q) {
        h16x8 aq[2], bk[2];
#pragma unroll
        for (int m = 0; m < 2; ++m) aq[m] = *(const h16x8*)(Qb + (m * 2 + q) * 1024 + lane * 16);
#pragma unroll
        for (int n = 0; n < 2; ++n) bk[n] = *(const h16x8*)(Kb + (n * 2 + q) * 1024 + lane * 16);
#pragma unroll
        for (int m = 0; m < 2; ++m)
#pragma unroll
            for (int n = 0; n < 2; ++n)
                s[m][n] = __builtin_amdgcn_mfma_f32_16x16x32_f16(aq[m], bk[n], s[m][n], 0, 0, 0);
    }

    float p[2][2][4];
#pragma unroll
    for (int m = 0; m < 2; ++m)
#pragma unroll
        for (int j = 0; j < 4; ++j) {
            float a0 = s[m][0][j] * 0.125f, a1 = s[m][1][j] * 0.125f;
            float mx = fmaxf(a0, a1);
            mx = fmaxf(mx, __shfl_xor(mx, 1));
            mx = fmaxf(mx, __shfl_xor(mx, 2));
            mx = fmaxf(mx, __shfl_xor(mx, 4));
            mx = fmaxf(mx, __shfl_xor(mx, 8));
            float e0 = __expf(a0 - mx), e1 = __expf(a1 - mx);
            float sm = e0 + e1;
            sm += __shfl_xor(sm, 1);
            sm += __shfl_xor(sm, 2);
            sm += __shfl_xor(sm, 4);
            sm += __shfl_xor(sm, 8);
            float inv = 1.f / sm;
            p[m][0][j] = e0 * inv;
            p[m][1][j] = e1 * inv;
        }

    char* Pb = smem + 98304 + w * 2048;
#pragma unroll
    for (int m = 0; m < 2; ++m)
#pragma unroll
        for (int n = 0; n < 2; ++n)
#pragma unroll
            for (int j = 0; j < 4; ++j)
                *(h16*)(Pb + m * 1024 + (kc * 4 + j + ((n * 2 + (rr >> 3)) & 3) * 16) * 16 + (lane & 7) * 2) = (h16)p[m][n][j];
    asm volatile("s_waitcnt lgkmcnt(0)" ::: "memory");
    SB0
    h16x8 ap[2];
#pragma unroll
    for (int m = 0; m < 2; ++m) ap[m] = *(const h16x8*)(Pb + m * 1024 + lane * 16);

    asm volatile("s_waitcnt vmcnt(0)" ::: "memory");
    SB0

    const char* Vb = Qb + 8192;
    f32x4 o[2][4];
#pragma unroll
    for (int m = 0; m < 2; ++m)
#pragma unroll
        for (int n = 0; n < 4; ++n) o[m][n] = (f32x4){0.f, 0.f, 0.f, 0.f};
#pragma unroll
    for (int n = 0; n < 4; ++n) {
        h16x8 bv;
#pragma unroll
        for (int e = 0; e < 8; ++e)
            bv[e] = *(const h16*)(Vb + ((kc >> 1) * 2 + (n >> 1)) * 1024
                                  + ((kc & 1) * 8 + e) * 16
                                  + ((n * 2 + (rr >> 3)) & 3) * 256 + (lane & 7) * 2);
#pragma unroll
        for (int m = 0; m < 2; ++m)
            o[m][n] = __builtin_amdgcn_mfma_f32_16x16x32_f16(ap[m], bv, o[m][n], 0, 0, 0);
    }

#pragma unroll
    for (int m = 0; m < 2; ++m)
#pragma unroll
        for (int n = 0; n < 4; ++n)
#pragma unroll
            for (int j = 0; j < 4; ++j)
                *(h16*)(smem + 98304 + (m * 16 + w * 2 + (n >> 1)) * 1024
                        + (kc * 4 + j + ((n & 1) * 2 + (rr >> 3)) * 16) * 16 + (lane & 7) * 2) = (h16)o[m][n][j];
    asm volatile("s_waitcnt lgkmcnt(0)" ::: "memory");
    SB0
    __builtin_amdgcn_s_barrier();
    SB0

    f32x4 acc[2][4];
#pragma unroll
    for (int m = 0; m < 2; ++m)
#pragma unroll
        for (int n = 0; n < 4; ++n) acc[m][n] = (f32x4){0.f, 0.f, 0.f, 0.f};

#define STGB(js, sl) { _Pragma("unroll") for (int u = 0; u < 4; ++u) { \
        const h16* s_ = Wo + (size_t)((((u << 3) + w) << 4) + rr) * DM + (js) * 32 + (kc << 3); \
        ldsload16(s_, smem + (sl) * 32768 + (((u << 3) + w) << 10) + (lane << 4)); } }

    STGB(0, 0) STGB(1, 1)
    int slotR = 0, slotW = 2;
    for (int sx = 0; sx < 15; ++sx) {
        asm volatile("s_waitcnt vmcnt(4)" ::: "memory");
        SB0
        __builtin_amdgcn_s_barrier();
        SB0
        h16x8 af[2], bf[4];
#pragma unroll
        for (int m = 0; m < 2; ++m)
            af[m] = *(const h16x8*)(smem + 98304 + (m * 16 + sx) * 1024 + (lane << 4));
#pragma unroll
        for (int n = 0; n < 4; ++n)
            bf[n] = *(const h16x8*)(smem + slotR * 32768 + (((w << 2) + n) << 10) + (lane << 4));
        asm volatile("s_waitcnt lgkmcnt(0)" ::: "memory");
        SB0
        if (sx + 2 < 16) STGB(sx + 2, slotW)
        __builtin_amdgcn_s_setprio(1);
#pragma unroll
        for (int m = 0; m < 2; ++m)
#pragma unroll
            for (int n = 0; n < 4; ++n)
                acc[m][n] = __builtin_amdgcn_mfma_f32_16x16x32_f16(af[m], bf[n], acc[m][n], 0, 0, 0);
        __builtin_amdgcn_s_setprio(0);
        SB0
        slotR = (slotR == 2) ? 0 : slotR + 1;
        slotW = (slotW == 2) ? 0 : slotW + 1;
    }
    {
        asm volatile("s_waitcnt vmcnt(0)" ::: "memory");
        SB0
        __builtin_amdgcn_s_barrier();
        SB0
        h16x8 af[2], bf[4];
#pragma unroll
        for (int m = 0; m < 2; ++m)
            af[m] = *(const h16x8*)(smem + 98304 + (m * 16 + 15) * 1024 + (lane << 4));
#pragma unroll
        for (int n = 0; n < 4; ++n)
            bf[n] = *(const h16x8*)(smem + slotR * 32768 + (((w << 2) + n) << 10) + (lane << 4));
        asm volatile("s_waitcnt lgkmcnt(0)" ::: "memory");
        SB0
#pragma unroll
        for (int m = 0; m < 2; ++m)
#pragma unroll
            for (int n = 0; n < 4; ++n)
                acc[m][n] = __builtin_amdgcn_mfma_f32_16x16x32_f16(af[m], bf[n], acc[m][n], 0, 0, 0);
    }
#undef STGB
#undef SB0
    __syncthreads();

    float* outl = (float*)smem;
    float bvv[4];
#pragma unroll
    for (int n = 0; n < 4; ++n)
        bvv[n] = bo[(w << 6) + n * 16 + rr];
#pragma unroll
    for (int m = 0; m < 2; ++m)
#pragma unroll
        for (int n = 0; n < 4; ++n)
#pragma unroll
            for (int j = 0; j < 4; ++j) {
                int r = m * 16 + kc * 4 + j;
                int c = (w << 6) + n * 16 + rr;
                outl[r * 516 + c] = acc[m][n][j] + bvv[n];
            }
    __syncthreads();
    {
        const int r = t >> 4, l = t & 15;
        const size_t grow = (row0 + r) * (size_t)DM;
        float v[32];
        float sum = 0.f, sq = 0.f;
#pragma unroll
        for (int i = 0; i < 32; ++i) {
            int col = l + (i << 4);
            float vv = outl[r * 516 + col] + (float)X[grow + col];
            v[i] = vv;
            sum += vv;
            sq += vv * vv;
        }
#pragma unroll
        for (int o2 = 8; o2; o2 >>= 1) {
            sum += __shfl_xor(sum, o2);
            sq  += __shfl_xor(sq, o2);
        }
        float mean = sum * (1.f / 512.f);
        float var = sq * (1.f / 512.f) - mean * mean;
        float inv = 1.f / sqrtf(var + 1e-5f);
#pragma unroll
        for (int i = 0; i < 32; ++i) {
            int col = l + (i << 4);
            X[grow + col] = (h16)((v[i] - mean) * inv * lw[col] + lb[col]);
        }
    }
}

// ---------------------------------------------------------------- x = LN(x + p0 + p1 + bias)*w + b (XCD-aligned rows)
__global__ __launch_bounds__(256) void k_addln_red(h16* __restrict__ x,
                                                   const h16* __restrict__ p0,
                                                   const h16* __restrict__ p1,
                                                   const float* __restrict__ bias,
                                                   const float* __restrict__ w,
                                                   const float* __restrict__ b) {
    size_t row = (size_t)(((blockIdx.x & 7) << 10) + (blockIdx.x >> 3));
    int t = threadIdx.x;
    size_t o0 = row * DM + t, o1 = o0 + 256;
    float v0 = (float)x[o0] + (float)p0[o0] + (float)p1[o0] + bias[t];
    float v1 = (float)x[o1] + (float)p0[o1] + (float)p1[o1] + bias[t + 256];
    float s = v0 + v1;
#pragma unroll
    for (int o = 32; o; o >>= 1) s += __shfl_xor(s, o);
    __shared__ float ss[4], qs[4];
    if ((t & 63) == 0) ss[t >> 6] = s;
    __syncthreads();
    float mean = (ss[0] + ss[1] + ss[2] + ss[3]) * (1.f / 512.f);
    float d0 = v0 - mean, d1 = v1 - mean;
    float qv = d0 * d0 + d1 * d1;
#pragma unroll
    for (int o = 32; o; o >>= 1) qv += __shfl_xor(qv, o);
    if ((t & 63) == 0) qs[t >> 6] = qv;
    __syncthreads();
    float var = (qs[0] + qs[1] + qs[2] + qs[3]) * (1.f / 512.f);
    float inv = 1.f / sqrtf(var + 1e-5f);
    x[o0] = (h16)(d0 * inv * w[t] + b[t]);
    x[o1] = (h16)(d1 * inv * w[t + 256] + b[t + 256]);
}

// ---------------------------------------------------------------- l2 rows: f32 in -> f16 out
__global__ __launch_bounds__(256) void k_l2rows_h(const float* __restrict__ in,
                                                  h16* __restrict__ outp) {
    size_t row = blockIdx.x;
    int t = threadIdx.x;
    float v0 = in[row * DM + t], v1 = in[row * DM + t + 256];
    float q = v0 * v0 + v1 * v1;
#pragma unroll
    for (int o = 32; o; o >>= 1) q += __shfl_xor(q, o);
    __shared__ float qs[4];
    if ((t & 63) == 0) qs[t >> 6] = q;
    __syncthreads();
    float n = sqrtf(qs[0] + qs[1] + qs[2] + qs[3]);
    float sc = 1.f / fmaxf(n, 1e-12f);
    outp[row * DM + t]       = (h16)(v0 * sc);
    outp[row * DM + t + 256] = (h16)(v1 * sc);
}

// ---------------------------------------------------------------- TOK rows (l2'd frames + video tokens)
__global__ __launch_bounds__(256) void k_build_tok_h(const float* __restrict__ frames,
                                                     const h16* __restrict__ X,
                                                     h16* __restrict__ TOK) {
    int rid = blockIdx.x;
    int j = rid / NTOK_V, tt = rid % NTOK_V;
    int t = threadIdx.x;
    float v0, v1;
    if (tt < 30) {
        const float* src = frames + ((size_t)j * 30 + tt) * DM;
        v0 = src[t]; v1 = src[t + 256];
    } else {
        const h16* src = X + ((size_t)j * 32 + (tt - 30)) * DM;
        v0 = (float)src[t]; v1 = (float)src[t + 256];
    }
    float q = v0 * v0 + v1 * v1;
#pragma unroll
    for (int o = 32; o; o >>= 1) q += __shfl_xor(q, o);
    __shared__ float qs[4];
    if ((t & 63) == 0) qs[t >> 6] = q;
    __syncthreads();
    float n = sqrtf(qs[0] + qs[1] + qs[2] + qs[3]);
    float sc = 1.f / fmaxf(n, 1e-12f);
    TOK[(size_t)rid * DM + t]       = (h16)(v0 * sc);
    TOK[(size_t)rid * DM + t + 256] = (h16)(v1 * sc);
}

// ---------------------------------------------------------------- max-reduce dots -> sims
__global__ __launch_bounds__(256) void k_sim_h(const h16* __restrict__ dots,
                                               float* __restrict__ out) {
    int i = blockIdx.x;
    int j = threadIdx.x;
    const h16* p = dots + (size_t)i * 15872 + (size_t)j * NTOK_V;
    float mf = -1e30f, mv = -1e30f;
#pragma unroll
    for (int tt = 0; tt < 30; ++tt) mf = fmaxf(mf, (float)p[tt]);
#pragma unroll
    for (int tt = 30; tt < 62; ++tt) mv = fmaxf(mv, (float)p[tt]);
    int o = i * 256 + j;
    out[o]          = mf + mv;
    out[65536 + o]  = mf;
    out[131072 + o] = mv;
}

// ---------------------------------------------------------------- launcher
extern "C" void kernel_launch(void* const* d_in, const int* in_sizes, int n_in,
                              void* d_out, int out_size, void* d_ws, size_t ws_size,
                              hipStream_t stream) {
    const float* text   = (const float*)d_in[0];
    const float* frames = (const float*)d_in[1];
    const float* expt   = (const float*)d_in[2];
    const float* Wqkv   = (const float*)d_in[3];
    const float* bqkv   = (const float*)d_in[4];
    const float* Wo     = (const float*)d_in[5];
    const float* bo     = (const float*)d_in[6];
    const float* ln1w   = (const float*)d_in[7];
    const float* ln1b   = (const float*)d_in[8];
    const float* W1     = (const float*)d_in[9];
    const float* b1     = (const float*)d_in[10];
    const float* W2     = (const float*)d_in[11];
    const float* b2     = (const float*)d_in[12];
    const float* ln2w   = (const float*)d_in[13];
    const float* ln2b   = (const float*)d_in[14];
    float* out = (float*)d_out;

    char* wsb = (char*)d_ws;
    const size_t MB = 1024 * 1024;
    h16* Xh    = (h16*)(wsb);              // 8 MB   [8192,512]
    h16* P0    = (h16*)(wsb + 8 * MB);     // 8 MB   split-K partial 0 (FF2)
    h16* P1    = (h16*)(wsb + 16 * MB);    // 8 MB   split-K partial 1
    h16* FFh   = (h16*)(wsb + 32 * MB);    // 32 MB  [8192,2048] (also QKV [8192,1536])
    h16* TOKh  = (h16*)(wsb + 32 * MB);    // alias FF (post-transformer)
    h16* DOTSh = (h16*)(wsb + 48 * MB);    // alias FF tail
    h16* Wh    = (h16*)(wsb + 64 * MB);    // 25 MB  all weights fp16 (contiguous)
    h16* QHATh = (h16*)(wsb + 90 * MB);    // 0.25 MB

    h16* Whqkv = Wh;                       // 4*1536*512
    h16* Who   = Whqkv + 3145728;          // 4*512*512
    h16* Wh1   = Who + 1048576;            // 4*2048*512
    h16* Wh2   = Wh1 + 4194304;            // 4*2048*512

    k_cvt_all<<<6144, 256, 0, stream>>>(Wqkv, Wo, W1, W2, Wh);
    k_concat_h<<<8192, 256, 0, stream>>>(frames, expt, Xh);

    for (int l = 0; l < 4; ++l) {
        const h16* Wqkv_l = Whqkv + (size_t)l * 786432;
        const h16* Wo_l   = Who   + (size_t)l * 262144;
        const h16* W1_l   = Wh1   + (size_t)l * 1048576;
        const h16* W2_l   = Wh2   + (size_t)l * 1048576;

        k_g8<0><<<dim3(6, 32, 1), 512, 0, stream>>>(
            Xh, 512, Wqkv_l, 512, bqkv + (size_t)l * 1536, FFh, 1536, 8192, 1536, 512);
        k_fattn<<<256, 512, 0, stream>>>(FFh, Wo_l, bo + (size_t)l * 512, Xh,
                                         ln1w + (size_t)l * 512, ln1b + (size_t)l * 512);
        k_g8<1><<<dim3(8, 32, 1), 512, 0, stream>>>(
            Xh, 512, W1_l, 512, b1 + (size_t)l * 2048, FFh, 2048, 8192, 2048, 512);
        k_g8n<<<dim3(4, 32, 2), 512, 0, stream>>>(
            FFh, 2048, W2_l, 2048, P0, 512, 8192, 512, 1024);
        k_addln_red<<<8192, 256, 0, stream>>>(Xh, P0, P1, b2 + (size_t)l * 512,
                                              ln2w + (size_t)l * 512, ln2b + (size_t)l * 512);
    }

    k_l2rows_h<<<256, 256, 0, stream>>>(text, QHATh);
    k_build_tok_h<<<256 * NTOK_V, 256, 0, stream>>>(frames, Xh, TOKh);
    k_hgemm<2><<<dim3(124, 2, 1), 512, 0, stream>>>(
        QHATh, 512, TOKh, 512, nullptr, DOTSh, 15872, 256, 15872, 512);
    k_sim_h<<<256, 256, 0, stream>>>(DOTSh, out);
}